// Round 12
// baseline (193.352 us; speedup 1.0000x reference)
//
#include <hip/hip_runtime.h>
#include <hip/hip_bf16.h>
#include <stdint.h>

typedef int  iv4   __attribute__((ext_vector_type(4)));    // 16 i8 operand
typedef int  iv16  __attribute__((ext_vector_type(16)));   // 32x32 i32 acc
typedef float f32x4 __attribute__((ext_vector_type(4)));

#define K_DIM 4096
#define N_DIM 4096
#define BKB   128     // K-tile depth in bytes (i8 elems)

// ---------------------------------------------------------------------------
// Kernel 1: x fp32 -> i8 with per-row scale sx[row] = rowmax/127.
// ---------------------------------------------------------------------------
__global__ __launch_bounds__(256) void convert_x_i8(const float* __restrict__ x,
                                                    char* __restrict__ xq,
                                                    float* __restrict__ sx) {
    const int row = blockIdx.x;
    const int tid = threadIdx.x;
    const float* xr = x + (long long)row * K_DIM + tid * 16;

    float4 v0 = *(const float4*)(xr + 0);
    float4 v1 = *(const float4*)(xr + 4);
    float4 v2 = *(const float4*)(xr + 8);
    float4 v3 = *(const float4*)(xr + 12);

    float m = fabsf(v0.x);
    m = fmaxf(m, fabsf(v0.y)); m = fmaxf(m, fabsf(v0.z)); m = fmaxf(m, fabsf(v0.w));
    m = fmaxf(m, fabsf(v1.x)); m = fmaxf(m, fabsf(v1.y)); m = fmaxf(m, fabsf(v1.z)); m = fmaxf(m, fabsf(v1.w));
    m = fmaxf(m, fabsf(v2.x)); m = fmaxf(m, fabsf(v2.y)); m = fmaxf(m, fabsf(v2.z)); m = fmaxf(m, fabsf(v2.w));
    m = fmaxf(m, fabsf(v3.x)); m = fmaxf(m, fabsf(v3.y)); m = fmaxf(m, fabsf(v3.z)); m = fmaxf(m, fabsf(v3.w));

    #pragma unroll
    for (int d = 32; d > 0; d >>= 1) m = fmaxf(m, __shfl_xor(m, d));
    __shared__ float red[4];
    const int lane = tid & 63, wid = tid >> 6;
    if (lane == 0) red[wid] = m;
    __syncthreads();
    float rmax = fmaxf(fmaxf(red[0], red[1]), fmaxf(red[2], red[3]));
    rmax = fmaxf(rmax, 1e-20f);
    if (tid == 0) sx[row] = rmax * (1.0f / 127.0f);

    const float q = 127.0f / rmax;
    union { char c[16]; int4 v; } u;
    const float vals[16] = {v0.x, v0.y, v0.z, v0.w, v1.x, v1.y, v1.z, v1.w,
                            v2.x, v2.y, v2.z, v2.w, v3.x, v3.y, v3.z, v3.w};
    #pragma unroll
    for (int i = 0; i < 16; ++i) u.c[i] = (char)__float2int_rn(vals[i] * q);
    *(int4*)(xq + (long long)row * K_DIM + tid * 16) = u.v;
}

// ---------------------------------------------------------------------------
// Kernel 2: weight row -> sign (i8, exact) + per-row mean|w| (fp32)
// ---------------------------------------------------------------------------
__global__ __launch_bounds__(256) void convert_w_i8(const float* __restrict__ w,
                                                    char* __restrict__ wq,
                                                    float* __restrict__ sw) {
    const int row = blockIdx.x;
    const int tid = threadIdx.x;
    const float* wr = w + (long long)row * K_DIM + tid * 16;

    float sum = 0.f;
    union { char c[16]; int4 v; } u;
    #pragma unroll
    for (int j = 0; j < 4; ++j) {
        float4 v = *(const float4*)(wr + j * 4);
        sum += fabsf(v.x) + fabsf(v.y) + fabsf(v.z) + fabsf(v.w);
        u.c[j * 4 + 0] = (char)((v.x > 0.f) - (v.x < 0.f));
        u.c[j * 4 + 1] = (char)((v.y > 0.f) - (v.y < 0.f));
        u.c[j * 4 + 2] = (char)((v.z > 0.f) - (v.z < 0.f));
        u.c[j * 4 + 3] = (char)((v.w > 0.f) - (v.w < 0.f));
    }
    *(int4*)(wq + (long long)row * K_DIM + tid * 16) = u.v;

    #pragma unroll
    for (int d = 32; d > 0; d >>= 1) sum += __shfl_down(sum, d);
    __shared__ float red[4];
    const int lane = tid & 63, wid = tid >> 6;
    if (lane == 0) red[wid] = sum;
    __syncthreads();
    if (tid == 0) sw[row] = (red[0] + red[1] + red[2] + red[3]) * (1.0f / (float)K_DIM);
}

// ===========================================================================
// 256x256 i8 GEMM @ BK=128 — round-9 structure VERBATIM, MFMA swapped to
// 32x32x32 i8 (4404 vs 3944 TOPS ceiling, half the instruction count).
// 8 waves 2x4, wave tile 128x64: A-frags 4 (32 rows), B-frags 2, 4 k-steps
// of K=32 -> 32 MFMA/wave/K-tile, acc iv16[4][2] = 128 regs (2 waves/SIMD).
// Phases (quadrant, a0 dies before a1 loads):
//   P0: read a0(8)+b0(4) | stage Ah1(t+1) | q00 acc[0..1][0]
//   P1: read b1(4)       | stage Bh0(t+1) | q01 acc[0..1][1]
//   P2: read a1(8)->a    | stage Bh1(t+1) | q11 acc[2..3][1]
//   P3: -                | stage Ah0(t+2)->CUR | q10 acc[2..3][0]; vmcnt(2)
// FIFO audit identical to round-9 (2 loads/stage, 10 outstanding at P3-end,
// vmcnt(2) drains exactly tile t+1). Swizzle/staging byte-identical to R9.
// Operand layout 32x32x32 i8: row=lane&31, k-chunk of 16B at (lane>>5)*16
// (same per-lane pattern class R5 validated numerically for bf16 32x32).
// C/D: col=lane&31, row=(r&3)+8*(r>>2)+4*(lane>>5)  [m74/m101 verified].
// ===========================================================================
struct SOp { const char* g; int row0; int kt; char* l; };

// stage one half-tile (128 rows x 128B): 2 gload_lds per wave (8 waves)
__device__ __forceinline__ void stage_half(const SOp s, int wid, int lane) {
    const int srcsw = ((lane & 7) ^ ((lane >> 3) & 7)) << 4;   // inverse swizzle
    #pragma unroll
    for (int op = 0; op < 2; ++op) {
        const int r = s.row0 + wid * 16 + op * 8 + (lane >> 3);
        const char* src = s.g + (long long)r * K_DIM + s.kt + srcsw;
        __builtin_amdgcn_global_load_lds(
            (const __attribute__((address_space(1))) void*)src,
            (__attribute__((address_space(3))) void*)(s.l + wid * 2048 + op * 1024),
            16, 0, 0);
    }
}

__device__ __forceinline__ iv4 ldsr(const char* t, int row, int slot) {
    return *(const iv4*)(t + row * 128 + ((slot ^ (row & 7)) << 4));
}

// A-half h: 2 frags (32 rows each) x 4 k-steps of K=32
__device__ __forceinline__ void read_ah(iv4 (&a)[2][4], const char* tA,
                                        int wm, int h, int l31, int ksel) {
    #pragma unroll
    for (int mi = 0; mi < 2; ++mi)
        #pragma unroll
        for (int ks = 0; ks < 4; ++ks)
            a[mi][ks] = ldsr(tA, wm * 128 + h * 64 + mi * 32 + l31, ks * 2 + ksel);
}
// B-half v: 1 frag x 4 k-steps
__device__ __forceinline__ void read_bv(iv4 (&b)[4], const char* tB,
                                        int wn, int v, int l31, int ksel) {
    #pragma unroll
    for (int ks = 0; ks < 4; ++ks)
        b[ks] = ldsr(tB, wn * 64 + v * 32 + l31, ks * 2 + ksel);
}

template<int H, int V>
__device__ __forceinline__ void mfma_q(iv16 (&acc)[4][2],
                                       const iv4 (&a)[2][4], const iv4 (&b)[4]) {
    #pragma unroll
    for (int ks = 0; ks < 4; ++ks)
        #pragma unroll
        for (int mi = 0; mi < 2; ++mi)
            acc[H * 2 + mi][V] = __builtin_amdgcn_mfma_i32_32x32x32_i8(
                a[mi][ks], b[ks], acc[H * 2 + mi][V], 0, 0, 0);
}

// S0..S3: per-phase stage enables. WN: 2 steady / 0 drain / -1 none.
template<bool S0, bool S1, bool S2, bool S3, int WN>
__device__ __forceinline__ void ktile(const char* __restrict__ cA,
                                      const char* __restrict__ cB,
                                      char* __restrict__ oA,
                                      char* __restrict__ oB,
                                      char* __restrict__ curA,
                                      const char* gA, const char* gB,
                                      int ktn, int ktn2,
                                      iv16 (&acc)[4][2],
                                      int wm, int wn, int wid, int lane)
{
    const int l31  = lane & 31;
    const int ksel = lane >> 5;
    iv4 a[2][4], b0[4], b1[4];

    // ---- P0: read a0 + b0 | stage Ah1(t+1) | q00
    read_ah(a, cA, wm, 0, l31, ksel);
    read_bv(b0, cB, wn, 0, l31, ksel);
    if constexpr (S0) stage_half({gA, 128, ktn, oA + 16384}, wid, lane);
    __builtin_amdgcn_s_barrier();
    __builtin_amdgcn_s_setprio(1);
    mfma_q<0, 0>(acc, a, b0);
    __builtin_amdgcn_s_setprio(0);
    __builtin_amdgcn_s_barrier();

    // ---- P1: read b1 | stage Bh0(t+1) | q01
    read_bv(b1, cB, wn, 1, l31, ksel);
    if constexpr (S1) stage_half({gB, 0, ktn, oB}, wid, lane);
    __builtin_amdgcn_s_barrier();
    __builtin_amdgcn_s_setprio(1);
    mfma_q<0, 1>(acc, a, b1);
    __builtin_amdgcn_s_setprio(0);
    __builtin_amdgcn_s_barrier();

    // ---- P2: read a1 (reuses a; a0 dead) | stage Bh1(t+1) | q11
    read_ah(a, cA, wm, 1, l31, ksel);
    if constexpr (S2) stage_half({gB, 128, ktn, oB + 16384}, wid, lane);
    __builtin_amdgcn_s_barrier();
    __builtin_amdgcn_s_setprio(1);
    mfma_q<1, 1>(acc, a, b1);
    __builtin_amdgcn_s_setprio(0);
    __builtin_amdgcn_s_barrier();

    // ---- P3: stage Ah0(t+2) into CURRENT buf (rows 0-127 last read @P2) | q10
    if constexpr (S3) stage_half({gA, 0, ktn2, curA}, wid, lane);
    __builtin_amdgcn_s_barrier();
    __builtin_amdgcn_s_setprio(1);
    mfma_q<1, 0>(acc, a, b0);
    __builtin_amdgcn_s_setprio(0);
    if constexpr (WN == 2)      asm volatile("s_waitcnt vmcnt(2)" ::: "memory");
    else if constexpr (WN == 0) asm volatile("s_waitcnt vmcnt(0)" ::: "memory");
    if constexpr (WN >= 0) __builtin_amdgcn_s_barrier();
}

__global__ __launch_bounds__(512, 2) void bitlinear_gemm_i8(
    const char* __restrict__ A, const char* __restrict__ B,
    const float* __restrict__ sx, const float* __restrict__ sw,
    float* __restrict__ C, int M)
{
    extern __shared__ char smem[];
    char* As0 = smem;              // [256][128B] each (32 KiB)
    char* As1 = smem + 32768;
    char* Bs0 = smem + 65536;
    char* Bs1 = smem + 98304;

    const int tid = threadIdx.x, lane = tid & 63, wid = tid >> 6;
    const int wm = wid >> 2, wn = wid & 3;

    // T1: bijective XCD swizzle (grid % 8 == 0 guaranteed by launcher)
    const int nbid = (int)blockIdx.x;
    const int cpx  = (int)gridDim.x >> 3;
    const int swz  = (nbid & 7) * cpx + (nbid >> 3);
    const int ntn  = N_DIM / 256;       // 16
    const int tm = swz / ntn, tn = swz % ntn;

    const char* gA = A + (long long)tm * 256 * K_DIM;
    const char* gB = B + (long long)tn * 256 * K_DIM;

    iv16 acc[4][2];
    #pragma unroll
    for (int i = 0; i < 4; ++i)
        #pragma unroll
        for (int j = 0; j < 2; ++j)
            #pragma unroll
            for (int r = 0; r < 16; ++r) acc[i][j][r] = 0;

    // prologue: t0 all 4 halves + Ah0(t1) = 10 loads/wave; vmcnt(2) drains t0.
    stage_half({gA,   0,   0, As0},         wid, lane);
    stage_half({gA, 128,   0, As0 + 16384}, wid, lane);
    stage_half({gB,   0,   0, Bs0},         wid, lane);
    stage_half({gB, 128,   0, Bs0 + 16384}, wid, lane);
    stage_half({gA,   0, BKB, As1},         wid, lane);
    asm volatile("s_waitcnt vmcnt(2)" ::: "memory");
    __builtin_amdgcn_s_barrier();

    // t=0 (buf0) steady
    ktile<true, true, true, true, 2>(As0, Bs0, As1, Bs1, As0,
                                     gA, gB, 1 * BKB, 2 * BKB,
                                     acc, wm, wn, wid, lane);
    // t=1..28 in pairs (buf1, buf0)
    #pragma unroll 1
    for (int i = 0; i < 14; ++i) {
        const int t = 2 * i + 1;
        ktile<true, true, true, true, 2>(As1, Bs1, As0, Bs0, As1,
                                         gA, gB, (t + 1) * BKB, (t + 2) * BKB,
                                         acc, wm, wn, wid, lane);
        ktile<true, true, true, true, 2>(As0, Bs0, As1, Bs1, As0,
                                         gA, gB, (t + 2) * BKB, (t + 3) * BKB,
                                         acc, wm, wn, wid, lane);
    }
    // t=29 (buf1) steady (stages t30 halves + Ah0(t31))
    ktile<true, true, true, true, 2>(As1, Bs1, As0, Bs0, As1,
                                     gA, gB, 30 * BKB, 31 * BKB,
                                     acc, wm, wn, wid, lane);
    // t=30 (buf0): stage t31's Ah1,Bh0,Bh1 only; vmcnt(0) drains all
    ktile<true, true, true, false, 0>(As0, Bs0, As1, Bs1, As0,
                                      gA, gB, 31 * BKB, 0,
                                      acc, wm, wn, wid, lane);
    // t=31 (buf1): plain compute, no trailing sync
    ktile<false, false, false, false, -1>(As1, Bs1, As0, Bs0, As1,
                                          gA, gB, 0, 0,
                                          acc, wm, wn, wid, lane);

    // epilogue: out = i32 * sw[col] * sx[row].
    // 32x32 C/D: col=lane&31, row=(r&3)+8*(r>>2)+4*(lane>>5)
    const long long m0 = (long long)tm * 256 + wm * 128;
    const long long n0 = (long long)tn * 256 + wn * 64;
    const int l31 = lane & 31, hi = lane >> 5;
    float swv[2];
    #pragma unroll
    for (int ni = 0; ni < 2; ++ni) swv[ni] = sw[n0 + ni * 32 + l31];
    #pragma unroll
    for (int mi = 0; mi < 4; ++mi) {
        #pragma unroll
        for (int r = 0; r < 16; ++r) {
            const long long row = m0 + mi * 32 + (r & 3) + 8 * (r >> 2) + 4 * hi;
            const float sxv = sx[row];
            #pragma unroll
            for (int ni = 0; ni < 2; ++ni) {
                const long long col = n0 + ni * 32 + l31;
                C[row * N_DIM + col] = (float)acc[mi][ni][r] * swv[ni] * sxv;
            }
        }
    }
}

// ---------------------------------------------------------------------------
// Naive fp32 fallback (shape/workspace escape hatch)
// ---------------------------------------------------------------------------
__global__ void bitlinear_naive_kernel(const float* __restrict__ x,
                                       const float* __restrict__ w,
                                       float* __restrict__ out, long long total) {
    const long long idx = (long long)blockIdx.x * blockDim.x + threadIdx.x;
    if (idx >= total) return;
    const long long m = idx / N_DIM;
    const long long o = idx % N_DIM;
    const float* xr = x + m * K_DIM;
    const float* wrow = w + o * K_DIM;
    float sum = 0.f, sa = 0.f;
    for (int k = 0; k < K_DIM; ++k) {
        float wv = wrow[k];
        sa += fabsf(wv);
        sum += xr[k] * ((wv > 0.f) ? 1.f : ((wv < 0.f) ? -1.f : 0.f));
    }
    out[idx] = sum * (sa * (1.0f / (float)K_DIM));
}

// ---------------------------------------------------------------------------
extern "C" void kernel_launch(void* const* d_in, const int* in_sizes, int n_in,
                              void* d_out, int out_size, void* d_ws, size_t ws_size,
                              hipStream_t stream) {
    const float* x = (const float*)d_in[0];   // [B,S,K] fp32
    const float* w = (const float*)d_in[1];   // [N,K] fp32
    float* out = (float*)d_out;               // [B,S,N] fp32

    const int M = in_sizes[0] / K_DIM;        // 8192

    const size_t xq_bytes = (size_t)M * K_DIM;
    const size_t wq_bytes = (size_t)N_DIM * K_DIM;
    const size_t sx_bytes = (size_t)M * sizeof(float);
    const size_t sw_bytes = (size_t)N_DIM * sizeof(float);

    if (ws_size < xq_bytes + wq_bytes + sx_bytes + sw_bytes || (M % 256) != 0) {
        const long long total = (long long)M * N_DIM;
        bitlinear_naive_kernel<<<(int)((total + 255) / 256), 256, 0, stream>>>(x, w, out, total);
        return;
    }

    char*  xq = (char*)d_ws;
    char*  wq = (char*)d_ws + xq_bytes;
    float* sx = (float*)((char*)d_ws + xq_bytes + wq_bytes);
    float* sw = (float*)((char*)d_ws + xq_bytes + wq_bytes + sx_bytes);

    convert_x_i8<<<M, 256, 0, stream>>>(x, xq, sx);
    convert_w_i8<<<N_DIM, 256, 0, stream>>>(w, wq, sw);

    hipFuncSetAttribute((const void*)bitlinear_gemm_i8,
                        hipFuncAttributeMaxDynamicSharedMemorySize, 131072);
    const int grid = (M / 256) * (N_DIM / 256);   // 32*16 = 512, %8==0
    bitlinear_gemm_i8<<<grid, 512, 131072, stream>>>(xq, wq, sx, sw, out, M);
}

// Round 13
// 173.312 us; speedup vs baseline: 1.1156x; 1.1156x over previous
//
#include <hip/hip_runtime.h>
#include <hip/hip_bf16.h>
#include <stdint.h>

typedef int  iv4   __attribute__((ext_vector_type(4)));   // 16 i8 operand / i32x4 acc
typedef float f32x4 __attribute__((ext_vector_type(4)));

#define K_DIM 4096
#define N_DIM 4096
#define BKB   128     // K-tile depth in bytes (i8 elems)

// ---------------------------------------------------------------------------
// Kernel 1: x fp32 -> i8 with per-row scale sx[row] = rowmax/127.
// ---------------------------------------------------------------------------
__global__ __launch_bounds__(256) void convert_x_i8(const float* __restrict__ x,
                                                    char* __restrict__ xq,
                                                    float* __restrict__ sx) {
    const int row = blockIdx.x;
    const int tid = threadIdx.x;
    const float* xr = x + (long long)row * K_DIM + tid * 16;

    float4 v0 = *(const float4*)(xr + 0);
    float4 v1 = *(const float4*)(xr + 4);
    float4 v2 = *(const float4*)(xr + 8);
    float4 v3 = *(const float4*)(xr + 12);

    float m = fabsf(v0.x);
    m = fmaxf(m, fabsf(v0.y)); m = fmaxf(m, fabsf(v0.z)); m = fmaxf(m, fabsf(v0.w));
    m = fmaxf(m, fabsf(v1.x)); m = fmaxf(m, fabsf(v1.y)); m = fmaxf(m, fabsf(v1.z)); m = fmaxf(m, fabsf(v1.w));
    m = fmaxf(m, fabsf(v2.x)); m = fmaxf(m, fabsf(v2.y)); m = fmaxf(m, fabsf(v2.z)); m = fmaxf(m, fabsf(v2.w));
    m = fmaxf(m, fabsf(v3.x)); m = fmaxf(m, fabsf(v3.y)); m = fmaxf(m, fabsf(v3.z)); m = fmaxf(m, fabsf(v3.w));

    #pragma unroll
    for (int d = 32; d > 0; d >>= 1) m = fmaxf(m, __shfl_xor(m, d));
    __shared__ float red[4];
    const int lane = tid & 63, wid = tid >> 6;
    if (lane == 0) red[wid] = m;
    __syncthreads();
    float rmax = fmaxf(fmaxf(red[0], red[1]), fmaxf(red[2], red[3]));
    rmax = fmaxf(rmax, 1e-20f);
    if (tid == 0) sx[row] = rmax * (1.0f / 127.0f);

    const float q = 127.0f / rmax;
    union { char c[16]; int4 v; } u;
    const float vals[16] = {v0.x, v0.y, v0.z, v0.w, v1.x, v1.y, v1.z, v1.w,
                            v2.x, v2.y, v2.z, v2.w, v3.x, v3.y, v3.z, v3.w};
    #pragma unroll
    for (int i = 0; i < 16; ++i) u.c[i] = (char)__float2int_rn(vals[i] * q);
    *(int4*)(xq + (long long)row * K_DIM + tid * 16) = u.v;
}

// ---------------------------------------------------------------------------
// Kernel 2: weight row -> sign (i8, exact) + per-row mean|w| (fp32)
// ---------------------------------------------------------------------------
__global__ __launch_bounds__(256) void convert_w_i8(const float* __restrict__ w,
                                                    char* __restrict__ wq,
                                                    float* __restrict__ sw) {
    const int row = blockIdx.x;
    const int tid = threadIdx.x;
    const float* wr = w + (long long)row * K_DIM + tid * 16;

    float sum = 0.f;
    union { char c[16]; int4 v; } u;
    #pragma unroll
    for (int j = 0; j < 4; ++j) {
        float4 v = *(const float4*)(wr + j * 4);
        sum += fabsf(v.x) + fabsf(v.y) + fabsf(v.z) + fabsf(v.w);
        u.c[j * 4 + 0] = (char)((v.x > 0.f) - (v.x < 0.f));
        u.c[j * 4 + 1] = (char)((v.y > 0.f) - (v.y < 0.f));
        u.c[j * 4 + 2] = (char)((v.z > 0.f) - (v.z < 0.f));
        u.c[j * 4 + 3] = (char)((v.w > 0.f) - (v.w < 0.f));
    }
    *(int4*)(wq + (long long)row * K_DIM + tid * 16) = u.v;

    #pragma unroll
    for (int d = 32; d > 0; d >>= 1) sum += __shfl_down(sum, d);
    __shared__ float red[4];
    const int lane = tid & 63, wid = tid >> 6;
    if (lane == 0) red[wid] = sum;
    __syncthreads();
    if (tid == 0) sw[row] = (red[0] + red[1] + red[2] + red[3]) * (1.0f / (float)K_DIM);
}

// ===========================================================================
// CHAMPION (round 9, restored verbatim): 256x256 i8 GEMM @ BK=128,
// m201-granularity phases (16 MFMA/phase), 8 waves 2x4, 128 KiB LDS dbuf.
//   P0: read a0(8)+b0(4) | stage Ah1(t+1) | q00(a0,b0)
//   P1: read b1(4)       | stage Bh0(t+1) | q01(a0,b1)
//   P2: read a1(8)->a    | stage Bh1(t+1) | q11(a1,b1)
//   P3: -                | stage Ah0(t+2)->CUR buf | q10(a1,b0); vmcnt(2)
// FIFO (2 loads/stage): end-P3 outstanding = Ah0(t+1)[P3(t-1)] +
//   {Ah1,Bh0,Bh1}(t+1) + Ah0(t+2) = 10 -> vmcnt(2) drains exactly tile t+1.
// Swizzle (128B rows, 8 x 16B slots): slot' = slot ^ (row&7), global source
// pre-swizzled (rule #21). Measured: 134.5 us GEMM, MfmaUtil 45%, 0 conflicts,
// absmax 0.043 — at the serial LDS+MFMA pipe-sum (5040 cyc/tile, model 4915).
// Post-R9 attempts (32x32 MFMA, fat waves, read-ahead, free-run) all lost.
// ===========================================================================
struct SOp { const char* g; int row0; int kt; char* l; };

// stage one half-tile (128 rows x 128B): 2 gload_lds per wave (8 waves)
__device__ __forceinline__ void stage_half(const SOp s, int wid, int lane) {
    const int srcsw = ((lane & 7) ^ ((lane >> 3) & 7)) << 4;   // inverse swizzle
    #pragma unroll
    for (int op = 0; op < 2; ++op) {
        const int r = s.row0 + wid * 16 + op * 8 + (lane >> 3);
        const char* src = s.g + (long long)r * K_DIM + s.kt + srcsw;
        __builtin_amdgcn_global_load_lds(
            (const __attribute__((address_space(1))) void*)src,
            (__attribute__((address_space(3))) void*)(s.l + wid * 2048 + op * 1024),
            16, 0, 0);
    }
}

__device__ __forceinline__ iv4 ldsr(const char* t, int row, int slot) {
    return *(const iv4*)(t + row * 128 + ((slot ^ (row & 7)) << 4));
}

// A-half h: 4 frags (16 rows each) x 2 k-halves (K=64 each)
__device__ __forceinline__ void read_ah(iv4 (&a)[4][2], const char* tA,
                                        int wm, int h, int l15, int c) {
    #pragma unroll
    for (int mi = 0; mi < 4; ++mi)
        #pragma unroll
        for (int kk = 0; kk < 2; ++kk)
            a[mi][kk] = ldsr(tA, wm * 128 + h * 64 + mi * 16 + l15, kk * 4 + c);
}
// B-half v: 2 frags x 2 k-halves
__device__ __forceinline__ void read_bv(iv4 (&b)[2][2], const char* tB,
                                        int wn, int v, int l15, int c) {
    #pragma unroll
    for (int ni = 0; ni < 2; ++ni)
        #pragma unroll
        for (int kk = 0; kk < 2; ++kk)
            b[ni][kk] = ldsr(tB, wn * 64 + v * 32 + ni * 16 + l15, kk * 4 + c);
}

template<int H, int V>
__device__ __forceinline__ void mfma_q(iv4 (&acc)[8][4],
                                       const iv4 (&a)[4][2], const iv4 (&b)[2][2]) {
    #pragma unroll
    for (int kk = 0; kk < 2; ++kk)
        #pragma unroll
        for (int mi = 0; mi < 4; ++mi)
            #pragma unroll
            for (int ni = 0; ni < 2; ++ni)
                acc[H * 4 + mi][V * 2 + ni] = __builtin_amdgcn_mfma_i32_16x16x64_i8(
                    a[mi][kk], b[ni][kk], acc[H * 4 + mi][V * 2 + ni], 0, 0, 0);
}

// S0..S3: per-phase stage enables. WN: 2 steady / 0 drain / -1 none.
template<bool S0, bool S1, bool S2, bool S3, int WN>
__device__ __forceinline__ void ktile(const char* __restrict__ cA,
                                      const char* __restrict__ cB,
                                      char* __restrict__ oA,
                                      char* __restrict__ oB,
                                      char* __restrict__ curA,
                                      const char* gA, const char* gB,
                                      int ktn, int ktn2,
                                      iv4 (&acc)[8][4],
                                      int wm, int wn, int wid, int lane)
{
    const int l15 = lane & 15;
    const int c   = lane >> 4;
    iv4 a[4][2], b0[2][2], b1[2][2];

    // ---- P0: read a0 + b0 | stage Ah1(t+1) | q00
    read_ah(a, cA, wm, 0, l15, c);
    read_bv(b0, cB, wn, 0, l15, c);
    if constexpr (S0) stage_half({gA, 128, ktn, oA + 16384}, wid, lane);
    __builtin_amdgcn_s_barrier();
    __builtin_amdgcn_s_setprio(1);
    mfma_q<0, 0>(acc, a, b0);
    __builtin_amdgcn_s_setprio(0);
    __builtin_amdgcn_s_barrier();

    // ---- P1: read b1 | stage Bh0(t+1) | q01
    read_bv(b1, cB, wn, 1, l15, c);
    if constexpr (S1) stage_half({gB, 0, ktn, oB}, wid, lane);
    __builtin_amdgcn_s_barrier();
    __builtin_amdgcn_s_setprio(1);
    mfma_q<0, 1>(acc, a, b1);
    __builtin_amdgcn_s_setprio(0);
    __builtin_amdgcn_s_barrier();

    // ---- P2: read a1 (reuses a regs; a0 dead) | stage Bh1(t+1) | q11
    read_ah(a, cA, wm, 1, l15, c);
    if constexpr (S2) stage_half({gB, 128, ktn, oB + 16384}, wid, lane);
    __builtin_amdgcn_s_barrier();
    __builtin_amdgcn_s_setprio(1);
    mfma_q<1, 1>(acc, a, b1);
    __builtin_amdgcn_s_setprio(0);
    __builtin_amdgcn_s_barrier();

    // ---- P3: stage Ah0(t+2) into CURRENT buf (rows 0-127 last read @P2) | q10
    if constexpr (S3) stage_half({gA, 0, ktn2, curA}, wid, lane);
    __builtin_amdgcn_s_barrier();
    __builtin_amdgcn_s_setprio(1);
    mfma_q<1, 0>(acc, a, b0);
    __builtin_amdgcn_s_setprio(0);
    if constexpr (WN == 2)      asm volatile("s_waitcnt vmcnt(2)" ::: "memory");
    else if constexpr (WN == 0) asm volatile("s_waitcnt vmcnt(0)" ::: "memory");
    if constexpr (WN >= 0) __builtin_amdgcn_s_barrier();
}

__global__ __launch_bounds__(512, 2) void bitlinear_gemm_i8(
    const char* __restrict__ A, const char* __restrict__ B,
    const float* __restrict__ sx, const float* __restrict__ sw,
    float* __restrict__ C, int M)
{
    extern __shared__ char smem[];
    char* As0 = smem;              // [256][128B] each (32 KiB)
    char* As1 = smem + 32768;
    char* Bs0 = smem + 65536;
    char* Bs1 = smem + 98304;

    const int tid = threadIdx.x, lane = tid & 63, wid = tid >> 6;
    const int wm = wid >> 2, wn = wid & 3;

    // T1: bijective XCD swizzle (grid % 8 == 0 guaranteed by launcher)
    const int nbid = (int)blockIdx.x;
    const int cpx  = (int)gridDim.x >> 3;
    const int swz  = (nbid & 7) * cpx + (nbid >> 3);
    const int ntn  = N_DIM / 256;       // 16
    const int tm = swz / ntn, tn = swz % ntn;

    const char* gA = A + (long long)tm * 256 * K_DIM;
    const char* gB = B + (long long)tn * 256 * K_DIM;

    iv4 acc[8][4];
    #pragma unroll
    for (int i = 0; i < 8; ++i)
        #pragma unroll
        for (int j = 0; j < 4; ++j) acc[i][j] = (iv4){0, 0, 0, 0};

    // prologue: t0 all 4 halves + Ah0(t1) = 10 loads/wave; vmcnt(2) drains t0.
    stage_half({gA,   0,   0, As0},         wid, lane);
    stage_half({gA, 128,   0, As0 + 16384}, wid, lane);
    stage_half({gB,   0,   0, Bs0},         wid, lane);
    stage_half({gB, 128,   0, Bs0 + 16384}, wid, lane);
    stage_half({gA,   0, BKB, As1},         wid, lane);
    asm volatile("s_waitcnt vmcnt(2)" ::: "memory");
    __builtin_amdgcn_s_barrier();

    // t=0 (buf0) steady
    ktile<true, true, true, true, 2>(As0, Bs0, As1, Bs1, As0,
                                     gA, gB, 1 * BKB, 2 * BKB,
                                     acc, wm, wn, wid, lane);
    // t=1..28 in pairs (buf1, buf0)
    #pragma unroll 1
    for (int i = 0; i < 14; ++i) {
        const int t = 2 * i + 1;
        ktile<true, true, true, true, 2>(As1, Bs1, As0, Bs0, As1,
                                         gA, gB, (t + 1) * BKB, (t + 2) * BKB,
                                         acc, wm, wn, wid, lane);
        ktile<true, true, true, true, 2>(As0, Bs0, As1, Bs1, As0,
                                         gA, gB, (t + 2) * BKB, (t + 3) * BKB,
                                         acc, wm, wn, wid, lane);
    }
    // t=29 (buf1) steady (stages t30 halves + Ah0(t31))
    ktile<true, true, true, true, 2>(As1, Bs1, As0, Bs0, As1,
                                     gA, gB, 30 * BKB, 31 * BKB,
                                     acc, wm, wn, wid, lane);
    // t=30 (buf0): stage t31's Ah1,Bh0,Bh1 only; vmcnt(0) drains all
    ktile<true, true, true, false, 0>(As0, Bs0, As1, Bs1, As0,
                                      gA, gB, 31 * BKB, 0,
                                      acc, wm, wn, wid, lane);
    // t=31 (buf1): plain compute, no trailing sync
    ktile<false, false, false, false, -1>(As1, Bs1, As0, Bs0, As1,
                                          gA, gB, 0, 0,
                                          acc, wm, wn, wid, lane);

    // epilogue: out = i32 * sw[col] * sx[row]. C/D: col=lane&15, row=(lane>>4)*4+j
    const long long m0 = (long long)tm * 256 + wm * 128;
    const long long n0 = (long long)tn * 256 + wn * 64;
    float swv[4];
    #pragma unroll
    for (int ni = 0; ni < 4; ++ni) swv[ni] = sw[n0 + ni * 16 + (lane & 15)];
    #pragma unroll
    for (int mi = 0; mi < 8; ++mi) {
        const long long rowb = m0 + mi * 16 + (lane >> 4) * 4;
        float sxr[4];
        #pragma unroll
        for (int j = 0; j < 4; ++j) sxr[j] = sx[rowb + j];
        #pragma unroll
        for (int ni = 0; ni < 4; ++ni) {
            const long long col = n0 + ni * 16 + (lane & 15);
            #pragma unroll
            for (int j = 0; j < 4; ++j)
                C[(rowb + j) * N_DIM + col] = (float)acc[mi][ni][j] * swv[ni] * sxr[j];
        }
    }
}

// ---------------------------------------------------------------------------
// Naive fp32 fallback (shape/workspace escape hatch)
// ---------------------------------------------------------------------------
__global__ void bitlinear_naive_kernel(const float* __restrict__ x,
                                       const float* __restrict__ w,
                                       float* __restrict__ out, long long total) {
    const long long idx = (long long)blockIdx.x * blockDim.x + threadIdx.x;
    if (idx >= total) return;
    const long long m = idx / N_DIM;
    const long long o = idx % N_DIM;
    const float* xr = x + m * K_DIM;
    const float* wrow = w + o * K_DIM;
    float sum = 0.f, sa = 0.f;
    for (int k = 0; k < K_DIM; ++k) {
        float wv = wrow[k];
        sa += fabsf(wv);
        sum += xr[k] * ((wv > 0.f) ? 1.f : ((wv < 0.f) ? -1.f : 0.f));
    }
    out[idx] = sum * (sa * (1.0f / (float)K_DIM));
}

// ---------------------------------------------------------------------------
extern "C" void kernel_launch(void* const* d_in, const int* in_sizes, int n_in,
                              void* d_out, int out_size, void* d_ws, size_t ws_size,
                              hipStream_t stream) {
    const float* x = (const float*)d_in[0];   // [B,S,K] fp32
    const float* w = (const float*)d_in[1];   // [N,K] fp32
    float* out = (float*)d_out;               // [B,S,N] fp32

    const int M = in_sizes[0] / K_DIM;        // 8192

    const size_t xq_bytes = (size_t)M * K_DIM;
    const size_t wq_bytes = (size_t)N_DIM * K_DIM;
    const size_t sx_bytes = (size_t)M * sizeof(float);
    const size_t sw_bytes = (size_t)N_DIM * sizeof(float);

    if (ws_size < xq_bytes + wq_bytes + sx_bytes + sw_bytes || (M % 256) != 0) {
        const long long total = (long long)M * N_DIM;
        bitlinear_naive_kernel<<<(int)((total + 255) / 256), 256, 0, stream>>>(x, w, out, total);
        return;
    }

    char*  xq = (char*)d_ws;
    char*  wq = (char*)d_ws + xq_bytes;
    float* sx = (float*)((char*)d_ws + xq_bytes + wq_bytes);
    float* sw = (float*)((char*)d_ws + xq_bytes + wq_bytes + sx_bytes);

    convert_x_i8<<<M, 256, 0, stream>>>(x, xq, sx);
    convert_w_i8<<<N_DIM, 256, 0, stream>>>(w, wq, sw);

    hipFuncSetAttribute((const void*)bitlinear_gemm_i8,
                        hipFuncAttributeMaxDynamicSharedMemorySize, 131072);
    const int grid = (M / 256) * (N_DIM / 256);   // 32*16 = 512, %8==0
    bitlinear_gemm_i8<<<grid, 512, 131072, stream>>>(xq, wq, sx, sw, out, M);
}